// Round 1
// baseline (2152.473 us; speedup 1.0000x reference)
//
#include <hip/hip_runtime.h>
#include <hip/hip_bf16.h>
#include <math.h>

// ---------------- constants ----------------
#define NTOK   1568
#define BATCH  2
#define HID    1024
#define NHEAD  16
#define HD     64
#define MLPD   4096
#define NLAYER 4
#define ROWS   (BATCH*NTOK)   // 3136
#define CONVK  1536

typedef __bf16 bf16x8 __attribute__((ext_vector_type(8)));
typedef float  f32x4  __attribute__((ext_vector_type(4)));

__device__ __forceinline__ unsigned short f2b(float f) {
  unsigned int u = __float_as_uint(f);
  unsigned int r = u + 0x7FFFu + ((u >> 16) & 1u);   // RNE
  return (unsigned short)(r >> 16);
}

// async global->LDS 16B; lds ptr must be wave-uniform base (HW adds lane*16)
__device__ __forceinline__ void async16(const unsigned short* g, unsigned short* l) {
  __builtin_amdgcn_global_load_lds(
      (__attribute__((address_space(1))) void*)(void*)g,
      (__attribute__((address_space(3))) void*)(void*)l, 16, 0, 0);
}

// ---------------- fp32 -> bf16 cast (x4 vectorized, grid-stride) ----------------
__global__ __launch_bounds__(256) void cast4_k(const float* __restrict__ s,
                                               unsigned short* __restrict__ d,
                                               long long n4) {
  long long i = (long long)blockIdx.x * 256 + threadIdx.x;
  long long stride = (long long)gridDim.x * 256;
  for (; i < n4; i += stride) {
    float4 v = ((const float4*)s)[i];
    *(ushort4*)(d + i * 4) = make_ushort4(f2b(v.x), f2b(v.y), f2b(v.z), f2b(v.w));
  }
}

// ---------------- im2col for the tubelet conv (non-overlapping patches) ----------------
// A[row=b*1568+t][col=c*512+td*256+ph*16+pw] = pv[b][2d+td][c][16hh+ph][16ww+pw]
__global__ __launch_bounds__(256) void im2col_k(const float* __restrict__ pv,
                                                unsigned short* __restrict__ A) {
  int idx = blockIdx.x * 256 + threadIdx.x;       // exactly ROWS*CONVK threads
  int row = idx / CONVK, col = idx % CONVK;
  int b = row / NTOK, t = row % NTOK;
  int d = t / 196, r = t % 196, hh = r / 14, ww = r % 14;
  int c = col >> 9, r2 = col & 511, td = r2 >> 8, ph = (r2 >> 4) & 15, pw = r2 & 15;
  int frame = 2 * d + td;
  const float* src = pv + ((((long long)b * 16 + frame) * 3 + c) * 224 + (hh * 16 + ph)) * 224
                        + (ww * 16 + pw);
  A[idx] = f2b(*src);
}

// ---------------- GEMM: C[M,N] = A[M,K](bf16) * B[N,K]^T(bf16) + bias ----------------
// EPI: 0 = fp32 out; 1 = fp32 out + resid; 2 = bf16 out; 3 = exact-GELU -> bf16 out
template <int EPI>
__global__ __launch_bounds__(256) void gemm_bt(const unsigned short* __restrict__ A,
                                               const unsigned short* __restrict__ B,
                                               const float* __restrict__ bias,
                                               const float* __restrict__ resid,
                                               float* __restrict__ outF,
                                               unsigned short* __restrict__ outB,
                                               int M, int N, int K) {
  __shared__ unsigned short As[128 * 32];
  __shared__ unsigned short Bs[128 * 32];
  const int tid = threadIdx.x;
  const int lane = tid & 63;
  const int w = tid >> 6;
  const int wm = (w >> 1) * 64, wn = (w & 1) * 64;
  const int l15 = lane & 15, l4 = lane >> 4;
  const int bm = blockIdx.y, bn = blockIdx.x;
  const int wbase = tid & ~63;   // wave-uniform

  f32x4 acc[4][4] = {};

  for (int k0 = 0; k0 < K; k0 += 32) {
    __syncthreads();   // previous tile's reads done before overwrite
#pragma unroll
    for (int it = 0; it < 2; ++it) {
      int c = it * 256 + tid;
      int rowA = bm * 128 + (c >> 2);
      if (rowA >= M) rowA = M - 1;                 // clamp; stores guarded later
      async16(A + (size_t)rowA * K + k0 + (c & 3) * 8, &As[(it * 256 + wbase) * 8]);
      int rowB = bn * 128 + (c >> 2);              // N always multiple of 128
      async16(B + (size_t)rowB * K + k0 + (c & 3) * 8, &Bs[(it * 256 + wbase) * 8]);
    }
    __syncthreads();   // drains vmcnt -> LDS populated

    bf16x8 af[4], bfr[4];
#pragma unroll
    for (int i = 0; i < 4; ++i) af[i]  = *(const bf16x8*)&As[(wm + i * 16 + l15) * 32 + l4 * 8];
#pragma unroll
    for (int j = 0; j < 4; ++j) bfr[j] = *(const bf16x8*)&Bs[(wn + j * 16 + l15) * 32 + l4 * 8];
#pragma unroll
    for (int i = 0; i < 4; ++i)
#pragma unroll
      for (int j = 0; j < 4; ++j)
        acc[i][j] = __builtin_amdgcn_mfma_f32_16x16x32_bf16(af[i], bfr[j], acc[i][j], 0, 0, 0);
  }

#pragma unroll
  for (int i = 0; i < 4; ++i) {
    int rowb = bm * 128 + wm + i * 16 + l4 * 4;
#pragma unroll
    for (int r = 0; r < 4; ++r) {
      int rr = rowb + r;
      if (rr >= M) continue;
#pragma unroll
      for (int j = 0; j < 4; ++j) {
        int col = bn * 128 + wn + j * 16 + l15;
        float v = acc[i][j][r] + bias[col];
        size_t o = (size_t)rr * N + col;
        if (EPI == 0) outF[o] = v;
        else if (EPI == 1) outF[o] = v + resid[o];
        else if (EPI == 2) outB[o] = f2b(v);
        else { float ge = 0.5f * v * (1.0f + erff(v * 0.70710678118654752f)); outB[o] = f2b(ge); }
      }
    }
  }
}

// ---------------- LayerNorm (row=1024) ----------------
template <int OUT_BF16>
__global__ __launch_bounds__(256) void ln_k(const float* __restrict__ x,
                                            const float* __restrict__ g,
                                            const float* __restrict__ b,
                                            unsigned short* __restrict__ oB,
                                            float* __restrict__ oF) {
  __shared__ float red[8];
  const int row = blockIdx.x, tid = threadIdx.x;
  const float4 v = ((const float4*)(x + (size_t)row * HID))[tid];
  float s = v.x + v.y + v.z + v.w;
  float q = v.x * v.x + v.y * v.y + v.z * v.z + v.w * v.w;
  for (int off = 32; off; off >>= 1) { s += __shfl_xor(s, off); q += __shfl_xor(q, off); }
  if ((tid & 63) == 0) { red[tid >> 6] = s; red[4 + (tid >> 6)] = q; }
  __syncthreads();
  float ts = red[0] + red[1] + red[2] + red[3];
  float tq = red[4] + red[5] + red[6] + red[7];
  float mu = ts * (1.0f / HID);
  float var = tq * (1.0f / HID) - mu * mu;
  float rs = rsqrtf(var + 1e-6f);
  int col = tid * 4;
  float o0 = (v.x - mu) * rs * g[col + 0] + b[col + 0];
  float o1 = (v.y - mu) * rs * g[col + 1] + b[col + 1];
  float o2 = (v.z - mu) * rs * g[col + 2] + b[col + 2];
  float o3 = (v.w - mu) * rs * g[col + 3] + b[col + 3];
  if (OUT_BF16) {
    *(ushort4*)(oB + (size_t)row * HID + col) = make_ushort4(f2b(o0), f2b(o1), f2b(o2), f2b(o3));
  } else {
    *(float4*)(oF + (size_t)row * HID + col) = make_float4(o0, o1, o2, o3);
  }
}

// ---------------- RoPE (VJEPA2 tiled-sin/cos * interleaved rotate-half) + bf16 cast ----------------
__global__ __launch_bounds__(256) void rope_k(const float* __restrict__ q,
                                              const float* __restrict__ k,
                                              unsigned short* __restrict__ qo,
                                              unsigned short* __restrict__ ko) {
  const float* src = blockIdx.y ? k : q;
  unsigned short* dst = blockIdx.y ? ko : qo;
  int idx = blockIdx.x * 256 + threadIdx.x;     // ROWS*512 exactly
  int row = idx >> 9;
  int pr = idx & 511;
  int head = pr >> 5;
  int d0 = (pr & 31) * 2;
  int t = row % NTOK;
  size_t base = (size_t)row * HID + head * 64 + d0;
  float x0 = src[base], x1 = src[base + 1];
  float o0, o1;
  if (d0 >= 60) { o0 = x0; o1 = x1; }
  else {
    int region = d0 / 20;
    int j0 = d0 - region * 20;
    int pos = (region == 0) ? (t / 196) : (region == 1 ? ((t % 196) / 14) : (t % 14));
    float fp = (float)pos;
    const float LG = 0.9210340371976184f;  // ln(10000)/10
    int i0 = j0 % 10, i1 = (j0 + 1) % 10;
    float f0 = expf(-LG * (float)i0) * fp;
    float f1 = expf(-LG * (float)i1) * fp;
    // out[2i]   = x0*cos(f[2i%10])   - x1*sin(f[2i%10])
    // out[2i+1] = x1*cos(f[2i+1%10]) + x0*sin(f[2i+1%10])
    o0 = x0 * cosf(f0) - x1 * sinf(f0);
    o1 = x1 * cosf(f1) + x0 * sinf(f1);
  }
  dst[base] = f2b(o0); dst[base + 1] = f2b(o1);
}

// ---------------- flash attention (online softmax), bf16 MFMA ----------------
// grid (32 bh, 25 q-tiles), block 256 (4 waves); wave handles 16 q-rows
__global__ __launch_bounds__(256) void flash_k(const unsigned short* __restrict__ Q,
                                               const unsigned short* __restrict__ Kp,
                                               const unsigned short* __restrict__ Vp,
                                               unsigned short* __restrict__ O) {
  __shared__ unsigned short Ks[64 * 64];
  __shared__ unsigned short Vt[64 * 64];     // transposed: Vt[dim][key]
  __shared__ unsigned short Pl[4][16 * 64];  // per-wave P round-trip

  const int bh = blockIdx.x, qt = blockIdx.y;
  const int b = bh >> 4, head = bh & 15;
  const int tid = threadIdx.x, lane = tid & 63, w = tid >> 6;
  const int l15 = lane & 15, l4 = lane >> 4;
  const size_t rowbase = (size_t)b * NTOK;
  const int hoff = head * 64;

  // Q fragments (A-layout: m=l15, k=l4*8+j (+32))
  int qrow = qt * 64 + w * 16 + l15;
  int qrc = qrow < NTOK ? qrow : NTOK - 1;
  const unsigned short* qptr = Q + (rowbase + qrc) * HID + hoff + l4 * 8;
  bf16x8 qf0 = *(const bf16x8*)qptr;
  bf16x8 qf1 = *(const bf16x8*)(qptr + 32);

  f32x4 oacc[4] = {};
  float mrun[4], lrun[4];
#pragma unroll
  for (int r = 0; r < 4; ++r) { mrun[r] = -1e30f; lrun[r] = 0.0f; }

  for (int kt = 0; kt < 25; ++kt) {
    __syncthreads();
    // stage K tile (row-major [key][dim]) via 16B chunks
#pragma unroll
    for (int it = 0; it < 2; ++it) {
      int c = it * 256 + tid;
      int kl = c >> 3, doff = (c & 7) * 8;
      int kg = kt * 64 + kl;
      uint4 val = make_uint4(0, 0, 0, 0);
      if (kg < NTOK) val = *(const uint4*)(Kp + (rowbase + kg) * HID + hoff + doff);
      *(uint4*)&Ks[kl * 64 + doff] = val;
    }
    // stage V transposed
    {
      int key = tid >> 2, d0 = (tid & 3) * 16;
      int kg = kt * 64 + key;
      if (kg < NTOK) {
        const unsigned short* vp = Vp + (rowbase + kg) * HID + hoff + d0;
#pragma unroll
        for (int jj = 0; jj < 16; ++jj) Vt[(d0 + jj) * 64 + key] = vp[jj];
      } else {
#pragma unroll
        for (int jj = 0; jj < 16; ++jj) Vt[(d0 + jj) * 64 + key] = 0;
      }
    }
    __syncthreads();

    // S = Q·K^T  (16 rows x 64 keys per wave)
    f32x4 s[4] = {};
#pragma unroll
    for (int nt = 0; nt < 4; ++nt) {
      bf16x8 k0 = *(const bf16x8*)&Ks[(nt * 16 + l15) * 64 + l4 * 8];
      bf16x8 k1 = *(const bf16x8*)&Ks[(nt * 16 + l15) * 64 + 32 + l4 * 8];
      s[nt] = __builtin_amdgcn_mfma_f32_16x16x32_bf16(qf0, k0, s[nt], 0, 0, 0);
      s[nt] = __builtin_amdgcn_mfma_f32_16x16x32_bf16(qf1, k1, s[nt], 0, 0, 0);
    }
    // scale + mask + online softmax (rows live in 16-lane groups)
    float rmax[4] = {-1e30f, -1e30f, -1e30f, -1e30f};
#pragma unroll
    for (int nt = 0; nt < 4; ++nt) {
      int kg = kt * 64 + nt * 16 + l15;
      bool valid = kg < NTOK;
#pragma unroll
      for (int r = 0; r < 4; ++r) {
        float v = valid ? s[nt][r] * 0.125f : -1e30f;
        s[nt][r] = v;
        rmax[r] = fmaxf(rmax[r], v);
      }
    }
#pragma unroll
    for (int off = 1; off < 16; off <<= 1)
#pragma unroll
      for (int r = 0; r < 4; ++r) rmax[r] = fmaxf(rmax[r], __shfl_xor(rmax[r], off, 16));
    float alpha[4], rsum[4];
#pragma unroll
    for (int r = 0; r < 4; ++r) {
      float mn = fmaxf(mrun[r], rmax[r]);
      alpha[r] = __expf(mrun[r] - mn);
      mrun[r] = mn;
      float sum = 0.0f;
#pragma unroll
      for (int nt = 0; nt < 4; ++nt) {
        float p = __expf(s[nt][r] - mn);
        s[nt][r] = p;
        sum += p;
      }
      rsum[r] = sum;
    }
#pragma unroll
    for (int off = 1; off < 16; off <<= 1)
#pragma unroll
      for (int r = 0; r < 4; ++r) rsum[r] += __shfl_xor(rsum[r], off, 16);
#pragma unroll
    for (int r = 0; r < 4; ++r) lrun[r] = lrun[r] * alpha[r] + rsum[r];
#pragma unroll
    for (int nt = 0; nt < 4; ++nt)
#pragma unroll
      for (int r = 0; r < 4; ++r) oacc[nt][r] *= alpha[r];

    // P: C/D layout -> LDS -> A-operand layout
#pragma unroll
    for (int nt = 0; nt < 4; ++nt)
#pragma unroll
      for (int r = 0; r < 4; ++r)
        Pl[w][(l4 * 4 + r) * 64 + nt * 16 + l15] = f2b(s[nt][r]);
    __syncthreads();

    bf16x8 p0 = *(const bf16x8*)&Pl[w][l15 * 64 + l4 * 8];
    bf16x8 p1 = *(const bf16x8*)&Pl[w][l15 * 64 + 32 + l4 * 8];
#pragma unroll
    for (int nt = 0; nt < 4; ++nt) {
      bf16x8 v0 = *(const bf16x8*)&Vt[(nt * 16 + l15) * 64 + l4 * 8];
      bf16x8 v1 = *(const bf16x8*)&Vt[(nt * 16 + l15) * 64 + 32 + l4 * 8];
      oacc[nt] = __builtin_amdgcn_mfma_f32_16x16x32_bf16(p0, v0, oacc[nt], 0, 0, 0);
      oacc[nt] = __builtin_amdgcn_mfma_f32_16x16x32_bf16(p1, v1, oacc[nt], 0, 0, 0);
    }
  }

#pragma unroll
  for (int r = 0; r < 4; ++r) {
    int qr = qt * 64 + w * 16 + l4 * 4 + r;
    if (qr >= NTOK) continue;
    float inv = 1.0f / lrun[r];
#pragma unroll
    for (int nt = 0; nt < 4; ++nt)
      O[(rowbase + qr) * HID + hoff + nt * 16 + l15] = f2b(oacc[nt][r] * inv);
  }
}

// ---------------- host launch ----------------
extern "C" void kernel_launch(void* const* d_in, const int* in_sizes, int n_in,
                              void* d_out, int out_size, void* d_ws, size_t ws_size,
                              hipStream_t stream) {
  (void)in_sizes; (void)n_in; (void)out_size; (void)ws_size;
  const float* pv      = (const float*)d_in[0];
  const float* patch_w = (const float*)d_in[1];
  const float* patch_b = (const float*)d_in[2];
  const float* ln1_g   = (const float*)d_in[3];
  const float* ln1_b   = (const float*)d_in[4];
  const float* qw = (const float*)d_in[5];
  const float* qb = (const float*)d_in[6];
  const float* kw = (const float*)d_in[7];
  const float* kb = (const float*)d_in[8];
  const float* vw = (const float*)d_in[9];
  const float* vb = (const float*)d_in[10];
  const float* pw = (const float*)d_in[11];
  const float* pb = (const float*)d_in[12];
  const float* ln2_g = (const float*)d_in[13];
  const float* ln2_b = (const float*)d_in[14];
  const float* fc1w = (const float*)d_in[15];
  const float* fc1b = (const float*)d_in[16];
  const float* fc2w = (const float*)d_in[17];
  const float* fc2b = (const float*)d_in[18];
  const float* lnf_g = (const float*)d_in[19];
  const float* lnf_b = (const float*)d_in[20];

  char* wsp = (char*)d_ws;
  auto alloc = [&](size_t bytes) {
    char* p = wsp;
    wsp += (bytes + 255) & ~(size_t)255;
    return p;
  };
  // needs ~210 MB workspace total
  unsigned short* wPatch = (unsigned short*)alloc((size_t)1024 * 1536 * 2);
  unsigned short* wQ = (unsigned short*)alloc((size_t)NLAYER * HID * HID * 2);
  unsigned short* wK = (unsigned short*)alloc((size_t)NLAYER * HID * HID * 2);
  unsigned short* wV = (unsigned short*)alloc((size_t)NLAYER * HID * HID * 2);
  unsigned short* wP = (unsigned short*)alloc((size_t)NLAYER * HID * HID * 2);
  unsigned short* wF1 = (unsigned short*)alloc((size_t)NLAYER * MLPD * HID * 2);
  unsigned short* wF2 = (unsigned short*)alloc((size_t)NLAYER * HID * MLPD * 2);
  unsigned short* Aim = (unsigned short*)alloc((size_t)ROWS * CONVK * 2);
  float* h  = (float*)alloc((size_t)ROWS * HID * 4);
  unsigned short* xnb = (unsigned short*)alloc((size_t)ROWS * HID * 2);
  float* qf = (float*)alloc((size_t)ROWS * HID * 4);
  float* kf = (float*)alloc((size_t)ROWS * HID * 4);
  unsigned short* qb2 = (unsigned short*)alloc((size_t)ROWS * HID * 2);
  unsigned short* kb2 = (unsigned short*)alloc((size_t)ROWS * HID * 2);
  unsigned short* vb2 = (unsigned short*)alloc((size_t)ROWS * HID * 2);
  unsigned short* ob  = (unsigned short*)alloc((size_t)ROWS * HID * 2);
  unsigned short* mb  = (unsigned short*)alloc((size_t)ROWS * MLPD * 2);

  auto cast = [&](const float* s, unsigned short* d, long long n) {
    long long n4 = n / 4;
    int grid = (int)((n4 + 255) / 256);
    if (grid > 16384) grid = 16384;
    cast4_k<<<grid, 256, 0, stream>>>(s, d, n4);
  };
  cast(patch_w, wPatch, (long long)1024 * 1536);
  cast(qw, wQ, (long long)NLAYER * HID * HID);
  cast(kw, wK, (long long)NLAYER * HID * HID);
  cast(vw, wV, (long long)NLAYER * HID * HID);
  cast(pw, wP, (long long)NLAYER * HID * HID);
  cast(fc1w, wF1, (long long)NLAYER * MLPD * HID);
  cast(fc2w, wF2, (long long)NLAYER * HID * MLPD);

  im2col_k<<<(ROWS * CONVK) / 256, 256, 0, stream>>>(pv, Aim);
  // conv as GEMM -> h (fp32 residual stream)
  gemm_bt<0><<<dim3(HID / 128, (ROWS + 127) / 128), 256, 0, stream>>>(
      Aim, wPatch, patch_b, nullptr, h, nullptr, ROWS, HID, CONVK);

  for (int i = 0; i < NLAYER; ++i) {
    ln_k<1><<<ROWS, 256, 0, stream>>>(h, ln1_g + i * HID, ln1_b + i * HID, xnb, nullptr);
    gemm_bt<0><<<dim3(HID / 128, (ROWS + 127) / 128), 256, 0, stream>>>(
        xnb, wQ + (size_t)i * HID * HID, qb + i * HID, nullptr, qf, nullptr, ROWS, HID, HID);
    gemm_bt<0><<<dim3(HID / 128, (ROWS + 127) / 128), 256, 0, stream>>>(
        xnb, wK + (size_t)i * HID * HID, kb + i * HID, nullptr, kf, nullptr, ROWS, HID, HID);
    gemm_bt<2><<<dim3(HID / 128, (ROWS + 127) / 128), 256, 0, stream>>>(
        xnb, wV + (size_t)i * HID * HID, vb + i * HID, nullptr, nullptr, vb2, ROWS, HID, HID);
    rope_k<<<dim3((ROWS * 512) / 256, 2), 256, 0, stream>>>(qf, kf, qb2, kb2);
    flash_k<<<dim3(BATCH * NHEAD, 25), 256, 0, stream>>>(qb2, kb2, vb2, ob);
    gemm_bt<1><<<dim3(HID / 128, (ROWS + 127) / 128), 256, 0, stream>>>(
        ob, wP + (size_t)i * HID * HID, pb + i * HID, h, h, nullptr, ROWS, HID, HID);
    ln_k<1><<<ROWS, 256, 0, stream>>>(h, ln2_g + i * HID, ln2_b + i * HID, xnb, nullptr);
    gemm_bt<3><<<dim3(MLPD / 128, (ROWS + 127) / 128), 256, 0, stream>>>(
        xnb, wF1 + (size_t)i * MLPD * HID, fc1b + i * MLPD, nullptr, nullptr, mb, ROWS, MLPD, HID);
    gemm_bt<1><<<dim3(HID / 128, (ROWS + 127) / 128), 256, 0, stream>>>(
        mb, wF2 + (size_t)i * HID * MLPD, fc2b + i * HID, h, h, nullptr, ROWS, HID, MLPD);
  }
  ln_k<0><<<ROWS, 256, 0, stream>>>(h, lnf_g, lnf_b, nullptr, (float*)d_out);
}

// Round 2
// 1944.180 us; speedup vs baseline: 1.1071x; 1.1071x over previous
//
#include <hip/hip_runtime.h>
#include <math.h>

// ---------------- constants ----------------
#define NTOK   1568
#define BATCH  2
#define HID    1024
#define MLPD   4096
#define NLAYER 4
#define ROWS   (BATCH*NTOK)   // 3136
#define CONVK  1536

typedef __bf16 bf16x8 __attribute__((ext_vector_type(8)));
typedef float  f32x4  __attribute__((ext_vector_type(4)));

__device__ __forceinline__ unsigned short f2b(float f) {
  unsigned int u = __float_as_uint(f);
  unsigned int r = u + 0x7FFFu + ((u >> 16) & 1u);   // RNE
  return (unsigned short)(r >> 16);
}
__device__ __forceinline__ float b2f(unsigned short s) {
  return __uint_as_float((unsigned int)s << 16);
}

// async global->LDS 16B; lds ptr must be wave-uniform base (HW adds lane*16)
__device__ __forceinline__ void async16(const unsigned short* g, unsigned short* l) {
  __builtin_amdgcn_global_load_lds(
      (__attribute__((address_space(1))) void*)(void*)g,
      (__attribute__((address_space(3))) void*)(void*)l, 16, 0, 0);
}

// ---------------- fp32 -> bf16 cast (x4 vectorized, grid-stride) ----------------
__global__ __launch_bounds__(256) void cast4_k(const float* __restrict__ s,
                                               unsigned short* __restrict__ d,
                                               long long n4) {
  long long i = (long long)blockIdx.x * 256 + threadIdx.x;
  long long stride = (long long)gridDim.x * 256;
  for (; i < n4; i += stride) {
    float4 v = ((const float4*)s)[i];
    *(ushort4*)(d + i * 4) = make_ushort4(f2b(v.x), f2b(v.y), f2b(v.z), f2b(v.w));
  }
}

// cast q/k/v weights into one concatenated per-layer buffer wQKV[L][3072][1024]
__global__ __launch_bounds__(256) void castqkv_k(const float* __restrict__ q,
                                                 const float* __restrict__ k,
                                                 const float* __restrict__ v,
                                                 unsigned short* __restrict__ dst) {
  const float* src = blockIdx.y == 0 ? q : (blockIdx.y == 1 ? k : v);
  long long i4 = (long long)blockIdx.x * 256 + threadIdx.x;   // exactly L*HH/4
  long long e = i4 * 4;
  int layer = (int)(e >> 20);                                  // HH = 1<<20
  long long de = e + ((long long)(2 * layer + blockIdx.y) << 20);
  float4 val = ((const float4*)src)[i4];
  *(ushort4*)(dst + de) = make_ushort4(f2b(val.x), f2b(val.y), f2b(val.z), f2b(val.w));
}

__global__ __launch_bounds__(256) void biascat_k(const float* __restrict__ qb,
                                                 const float* __restrict__ kb,
                                                 const float* __restrict__ vb,
                                                 float* __restrict__ dst) {
  int idx = blockIdx.x * 256 + threadIdx.x;   // L*3072
  int layer = idx / 3072, c = idx % 3072;
  float v = c < 1024 ? qb[layer * 1024 + c]
            : (c < 2048 ? kb[layer * 1024 + c - 1024] : vb[layer * 1024 + c - 2048]);
  dst[idx] = v;
}

// ---------------- im2col for the tubelet conv ----------------
__global__ __launch_bounds__(256) void im2col_k(const float* __restrict__ pv,
                                                unsigned short* __restrict__ A) {
  int idx = blockIdx.x * 256 + threadIdx.x;       // exactly ROWS*CONVK threads
  int row = idx / CONVK, col = idx % CONVK;
  int b = row / NTOK, t = row % NTOK;
  int d = t / 196, r = t % 196, hh = r / 14, ww = r % 14;
  int c = col >> 9, r2 = col & 511, td = r2 >> 8, ph = (r2 >> 4) & 15, pw = r2 & 15;
  int frame = 2 * d + td;
  const float* src = pv + ((((long long)b * 16 + frame) * 3 + c) * 224 + (hh * 16 + ph)) * 224
                        + (ww * 16 + pw);
  A[idx] = f2b(*src);
}

// ---------------- GEMM: C[M,N] = A[M,K](bf16) * B[N,K]^T(bf16) + bias ----------------
// EPI: 0 = fp32 out; 1 = fp32 out + resid; 2 = bf16 out; 3 = exact-GELU -> bf16 out
template <int EPI>
__global__ __launch_bounds__(256) void gemm_bt(const unsigned short* __restrict__ A,
                                               const unsigned short* __restrict__ B,
                                               const float* __restrict__ bias,
                                               const float* __restrict__ resid,
                                               float* __restrict__ outF,
                                               unsigned short* __restrict__ outB,
                                               int M, int N, int K) {
  __shared__ unsigned short As[128 * 32];
  __shared__ unsigned short Bs[128 * 32];
  const int tid = threadIdx.x;
  const int lane = tid & 63;
  const int w = tid >> 6;
  const int wm = (w >> 1) * 64, wn = (w & 1) * 64;
  const int l15 = lane & 15, l4 = lane >> 4;
  const int bm = blockIdx.y, bn = blockIdx.x;
  const int wbase = tid & ~63;   // wave-uniform

  f32x4 acc[4][4] = {};

  for (int k0 = 0; k0 < K; k0 += 32) {
    __syncthreads();
#pragma unroll
    for (int it = 0; it < 2; ++it) {
      int c = it * 256 + tid;
      int rowA = bm * 128 + (c >> 2);
      if (rowA >= M) rowA = M - 1;
      async16(A + (size_t)rowA * K + k0 + (c & 3) * 8, &As[(it * 256 + wbase) * 8]);
      int rowB = bn * 128 + (c >> 2);
      async16(B + (size_t)rowB * K + k0 + (c & 3) * 8, &Bs[(it * 256 + wbase) * 8]);
    }
    __syncthreads();

    bf16x8 af[4], bfr[4];
#pragma unroll
    for (int i = 0; i < 4; ++i) af[i]  = *(const bf16x8*)&As[(wm + i * 16 + l15) * 32 + l4 * 8];
#pragma unroll
    for (int j = 0; j < 4; ++j) bfr[j] = *(const bf16x8*)&Bs[(wn + j * 16 + l15) * 32 + l4 * 8];
#pragma unroll
    for (int i = 0; i < 4; ++i)
#pragma unroll
      for (int j = 0; j < 4; ++j)
        acc[i][j] = __builtin_amdgcn_mfma_f32_16x16x32_bf16(af[i], bfr[j], acc[i][j], 0, 0, 0);
  }

#pragma unroll
  for (int i = 0; i < 4; ++i) {
    int rowb = bm * 128 + wm + i * 16 + l4 * 4;
#pragma unroll
    for (int r = 0; r < 4; ++r) {
      int rr = rowb + r;
      if (rr >= M) continue;
#pragma unroll
      for (int j = 0; j < 4; ++j) {
        int col = bn * 128 + wn + j * 16 + l15;
        float v = acc[i][j][r] + bias[col];
        size_t o = (size_t)rr * N + col;
        if (EPI == 0) outF[o] = v;
        else if (EPI == 1) outF[o] = v + resid[o];
        else if (EPI == 2) outB[o] = f2b(v);
        else { float ge = 0.5f * v * (1.0f + erff(v * 0.70710678118654752f)); outB[o] = f2b(ge); }
      }
    }
  }
}

// ---------------- LayerNorm (row=1024) ----------------
template <int OUT_BF16>
__global__ __launch_bounds__(256) void ln_k(const float* __restrict__ x,
                                            const float* __restrict__ g,
                                            const float* __restrict__ b,
                                            unsigned short* __restrict__ oB,
                                            float* __restrict__ oF) {
  __shared__ float red[8];
  const int row = blockIdx.x, tid = threadIdx.x;
  const float4 v = ((const float4*)(x + (size_t)row * HID))[tid];
  float s = v.x + v.y + v.z + v.w;
  float q = v.x * v.x + v.y * v.y + v.z * v.z + v.w * v.w;
  for (int off = 32; off; off >>= 1) { s += __shfl_xor(s, off); q += __shfl_xor(q, off); }
  if ((tid & 63) == 0) { red[tid >> 6] = s; red[4 + (tid >> 6)] = q; }
  __syncthreads();
  float ts = red[0] + red[1] + red[2] + red[3];
  float tq = red[4] + red[5] + red[6] + red[7];
  float mu = ts * (1.0f / HID);
  float var = tq * (1.0f / HID) - mu * mu;
  float rs = rsqrtf(var + 1e-6f);
  int col = tid * 4;
  float o0 = (v.x - mu) * rs * g[col + 0] + b[col + 0];
  float o1 = (v.y - mu) * rs * g[col + 1] + b[col + 1];
  float o2 = (v.z - mu) * rs * g[col + 2] + b[col + 2];
  float o3 = (v.w - mu) * rs * g[col + 3] + b[col + 3];
  if (OUT_BF16) {
    *(ushort4*)(oB + (size_t)row * HID + col) = make_ushort4(f2b(o0), f2b(o1), f2b(o2), f2b(o3));
  } else {
    *(float4*)(oF + (size_t)row * HID + col) = make_float4(o0, o1, o2, o3);
  }
}

// ---------------- QKV prep: RoPE(q,k)+scale -> head-major; V -> per-head transposed ----
// grid (25 token-tiles, 32 bh); block 256
__global__ __launch_bounds__(256) void qkvprep_k(const unsigned short* __restrict__ qkvb,
                                                 unsigned short* __restrict__ Qh,
                                                 unsigned short* __restrict__ Kh,
                                                 unsigned short* __restrict__ VT) {
  __shared__ unsigned short Vs[64 * 72];
  const int tile = blockIdx.x, bh = blockIdx.y;
  const int b = bh >> 4, head = bh & 15;
  const int tid = threadIdx.x;
  const int tl = tid >> 2, dc = tid & 3;
  const int tg = tile * 64 + tl;
  const int trc = tg < NTOK ? tg : NTOK - 1;
  const bool valid = tg < NTOK;
  const size_t srow = ((size_t)(b * NTOK + trc)) * 3072 + head * 64 + dc * 16;

  // V chunk -> LDS
  {
    uint4 v0 = *(const uint4*)(qkvb + srow + 2048);
    uint4 v1 = *(const uint4*)(qkvb + srow + 2048 + 8);
    *(uint4*)&Vs[tl * 72 + dc * 16] = v0;
    *(uint4*)&Vs[tl * 72 + dc * 16 + 8] = v1;
  }

  // RoPE on q,k (8 pairs per thread)
  const int t = trc;
  const int dpos = t / 196, rem = t - dpos * 196, hpos = rem / 14, wpos = rem - hpos * 14;
  const float LG = 0.9210340371976184f;  // ln(10000)/10
  union V16 { uint4 u[2]; unsigned short s[16]; };
  V16 qin, kin, qout, kout;
  qin.u[0] = *(const uint4*)(qkvb + srow);
  qin.u[1] = *(const uint4*)(qkvb + srow + 8);
  kin.u[0] = *(const uint4*)(qkvb + srow + 1024);
  kin.u[1] = *(const uint4*)(qkvb + srow + 1024 + 8);
#pragma unroll
  for (int p = 0; p < 8; ++p) {
    int d0 = dc * 16 + 2 * p;
    float qx0 = b2f(qin.s[2 * p]), qx1 = b2f(qin.s[2 * p + 1]);
    float kx0 = b2f(kin.s[2 * p]), kx1 = b2f(kin.s[2 * p + 1]);
    float qo0, qo1, ko0, ko1;
    if (d0 >= 60) { qo0 = qx0; qo1 = qx1; ko0 = kx0; ko1 = kx1; }
    else {
      int region = d0 / 20;
      int j0 = d0 - region * 20;
      int pos = region == 0 ? dpos : (region == 1 ? hpos : wpos);
      float fp = (float)pos;
      int i0 = j0 % 10, i1 = (j0 + 1) % 10;
      float f0 = expf(-LG * (float)i0) * fp;
      float f1 = expf(-LG * (float)i1) * fp;
      float c0 = cosf(f0), s0 = sinf(f0), c1 = cosf(f1), s1 = sinf(f1);
      qo0 = qx0 * c0 - qx1 * s0; qo1 = qx1 * c1 + qx0 * s1;
      ko0 = kx0 * c0 - kx1 * s0; ko1 = kx1 * c1 + kx0 * s1;
    }
    qout.s[2 * p]     = f2b(qo0 * 0.125f);     // fold attention scale into Q
    qout.s[2 * p + 1] = f2b(qo1 * 0.125f);
    kout.s[2 * p]     = f2b(ko0);
    kout.s[2 * p + 1] = f2b(ko1);
  }
  if (valid) {
    size_t drow = ((size_t)bh * NTOK + tg) * 64 + dc * 16;
    *(uint4*)(Qh + drow)     = qout.u[0];
    *(uint4*)(Qh + drow + 8) = qout.u[1];
    *(uint4*)(Kh + drow)     = kout.u[0];
    *(uint4*)(Kh + drow + 8) = kout.u[1];
  }
  __syncthreads();
  // V transpose out: thread = (dim, token-chunk)
  {
    int d = tid >> 2, tc = tid & 3;
    if (tile * 64 + tc * 16 < NTOK) {
      V16 o;
#pragma unroll
      for (int jj = 0; jj < 16; ++jj) o.s[jj] = Vs[(tc * 16 + jj) * 72 + d];
      unsigned short* dst = VT + ((size_t)bh * 64 + d) * NTOK + tile * 64 + tc * 16;
      *(uint4*)dst = o.u[0];
      *(uint4*)(dst + 8) = o.u[1];
    }
  }
}

// ---------------- flash attention v2: S^T = K·Q^T, O^T = V^T·P^T, no LDS in K-loop ----
// grid (32 bh, 25 q-tiles), block 256 (4 waves); wave owns 16 q-rows, loops 25 key-tiles
__global__ __launch_bounds__(256) void flash2_k(const unsigned short* __restrict__ Qh,
                                                const unsigned short* __restrict__ Kh,
                                                const unsigned short* __restrict__ VT,
                                                unsigned short* __restrict__ O) {
  __shared__ unsigned short Os[4][16 * 72];
  const int bh = blockIdx.x, qt = blockIdx.y;
  const int b = bh >> 4, head = bh & 15;
  const int tid = threadIdx.x, lane = tid & 63, w = tid >> 6;
  const int l15 = lane & 15, l4 = lane >> 4;
  const size_t hb = (size_t)bh * NTOK * 64;

  const int qrow = qt * 64 + w * 16 + l15;
  const int qrc = qrow < NTOK ? qrow : NTOK - 1;
  // Q as B-operand: lane n=l15 (qrow), elements k=dim=l4*8+j  -> contiguous
  bf16x8 q0 = *(const bf16x8*)(Qh + hb + (size_t)qrc * 64 + l4 * 8);
  bf16x8 q1 = *(const bf16x8*)(Qh + hb + (size_t)qrc * 64 + 32 + l4 * 8);

  f32x4 oacc[4] = {};          // O^T tiles: row dim=dt*16+l4*4+r, col qrow=l15
  float m = -1e30f, l = 0.0f;  // per-qrow (lane-uniform across l4 group)
  const unsigned short* vbp = VT + (size_t)bh * 64 * NTOK;

  for (int kt = 0; kt < 25; ++kt) {
    const int kb = kt * 64;
    f32x4 s[4] = {};           // S^T: row key=kb+nt*16+l4*4+r, col qrow=l15
#pragma unroll
    for (int nt = 0; nt < 4; ++nt) {
      int kr = kb + nt * 16 + l15;
      int krc = kr < NTOK ? kr : NTOK - 1;
      // K as A-operand: lane m=l15 (key), k=dim=l4*8+j -> contiguous
      bf16x8 k0 = *(const bf16x8*)(Kh + hb + (size_t)krc * 64 + l4 * 8);
      bf16x8 k1 = *(const bf16x8*)(Kh + hb + (size_t)krc * 64 + 32 + l4 * 8);
      s[nt] = __builtin_amdgcn_mfma_f32_16x16x32_bf16(k0, q0, s[nt], 0, 0, 0);
      s[nt] = __builtin_amdgcn_mfma_f32_16x16x32_bf16(k1, q1, s[nt], 0, 0, 0);
    }
    if (kb + 64 > NTOK) {      // mask invalid keys (last tile only)
#pragma unroll
      for (int nt = 0; nt < 4; ++nt)
#pragma unroll
        for (int r = 0; r < 4; ++r)
          if (kb + nt * 16 + l4 * 4 + r >= NTOK) s[nt][r] = -1e30f;
    }
    // online softmax: row = fixed l15 -> in-lane reduce + 2 shuffles over l4 group
    float rmax = s[0][0];
#pragma unroll
    for (int nt = 0; nt < 4; ++nt)
#pragma unroll
      for (int r = 0; r < 4; ++r) rmax = fmaxf(rmax, s[nt][r]);
    rmax = fmaxf(rmax, __shfl_xor(rmax, 16));
    rmax = fmaxf(rmax, __shfl_xor(rmax, 32));
    float mn = fmaxf(m, rmax);
    float alpha = __expf(m - mn);
    m = mn;
    float rsum = 0.0f;
#pragma unroll
    for (int nt = 0; nt < 4; ++nt)
#pragma unroll
      for (int r = 0; r < 4; ++r) {
        float p = __expf(s[nt][r] - mn);
        s[nt][r] = p;
        rsum += p;
      }
    rsum += __shfl_xor(rsum, 16);
    rsum += __shfl_xor(rsum, 32);
    l = l * alpha + rsum;
#pragma unroll
    for (int dt = 0; dt < 4; ++dt)
#pragma unroll
      for (int r = 0; r < 4; ++r) oacc[dt][r] *= alpha;   // alpha lane-uniform per qrow

    // P (C/D of S^T) -> P^T B-operand fragments via shuffles (no LDS, no barrier)
    unsigned pk01[4], pk23[4];
#pragma unroll
    for (int nt = 0; nt < 4; ++nt) {
      pk01[nt] = (unsigned)f2b(s[nt][0]) | ((unsigned)f2b(s[nt][1]) << 16);
      pk23[nt] = (unsigned)f2b(s[nt][2]) | ((unsigned)f2b(s[nt][3]) << 16);
    }
    const int srcA = ((l4 & 1) << 5) | l15;   // lane holding keys (l4&1)*8 + {0..3} of tile
    const int srcB = srcA + 16;               // keys (l4&1)*8 + {4..7}
    const bool hi = (l4 >> 1) != 0;           // tile select: nt' = 2kc + (l4>>1)
    union PB { unsigned u[4]; bf16x8 v; } pf[2];
#pragma unroll
    for (int kc = 0; kc < 2; ++kc) {
      unsigned t0, t1;
      t0 = __shfl(pk01[2 * kc], srcA); t1 = __shfl(pk01[2 * kc + 1], srcA);
      pf[kc].u[0] = hi ? t1 : t0;
      t0 = __shfl(pk23[2 * kc], srcA); t1 = __shfl(pk23[2 * kc + 1], srcA);
      pf[kc].u[1] = hi ? t1 : t0;
      t0 = __shfl(pk01[2 * kc], srcB); t1 = __shfl(pk01[2 * kc + 1], srcB);
      pf[kc].u[2] = hi ? t1 : t0;
      t0 = __shfl(pk23[2 * kc], srcB); t1 = __shfl(pk23[2 * kc + 1], srcB);
      pf[kc].u[3] = hi ? t1 : t0;
    }
    // O^T += V^T · P^T ; V^T as A-operand from VT (contiguous along keys)
#pragma unroll
    for (int dt = 0; dt < 4; ++dt) {
      const unsigned short* vr = vbp + (size_t)(dt * 16 + l15) * NTOK + kb;
      bf16x8 v0 = *(const bf16x8*)(vr + l4 * 8);
      bf16x8 v1 = *(const bf16x8*)(vr + 32 + l4 * 8);
      oacc[dt] = __builtin_amdgcn_mfma_f32_16x16x32_bf16(v0, pf[0].v, oacc[dt], 0, 0, 0);
      oacc[dt] = __builtin_amdgcn_mfma_f32_16x16x32_bf16(v1, pf[1].v, oacc[dt], 0, 0, 0);
    }
  }

  // epilogue: O^T -> per-wave LDS transpose -> coalesced store in [b][t][h][d] layout
  float inv = 1.0f / l;
#pragma unroll
  for (int dt = 0; dt < 4; ++dt)
#pragma unroll
    for (int r = 0; r < 4; ++r)
      Os[w][l15 * 72 + dt * 16 + l4 * 4 + r] = f2b(oacc[dt][r] * inv);
  // same-wave LDS write->read; compiler inserts lgkmcnt wait
  if (qrow < NTOK) {
    uint4 a  = *(const uint4*)&Os[w][l15 * 72 + l4 * 16];
    uint4 bq = *(const uint4*)&Os[w][l15 * 72 + l4 * 16 + 8];
    unsigned short* op = O + ((size_t)(b * NTOK + qrow)) * HID + head * 64;
    *(uint4*)(op + l4 * 16) = a;
    *(uint4*)(op + l4 * 16 + 8) = bq;
  }
}

// ---------------- host launch ----------------
extern "C" void kernel_launch(void* const* d_in, const int* in_sizes, int n_in,
                              void* d_out, int out_size, void* d_ws, size_t ws_size,
                              hipStream_t stream) {
  (void)in_sizes; (void)n_in; (void)out_size; (void)ws_size;
  const float* pv      = (const float*)d_in[0];
  const float* patch_w = (const float*)d_in[1];
  const float* patch_b = (const float*)d_in[2];
  const float* ln1_g   = (const float*)d_in[3];
  const float* ln1_b   = (const float*)d_in[4];
  const float* qw = (const float*)d_in[5];
  const float* qb = (const float*)d_in[6];
  const float* kw = (const float*)d_in[7];
  const float* kb = (const float*)d_in[8];
  const float* vw = (const float*)d_in[9];
  const float* vb = (const float*)d_in[10];
  const float* pw = (const float*)d_in[11];
  const float* pb = (const float*)d_in[12];
  const float* ln2_g = (const float*)d_in[13];
  const float* ln2_b = (const float*)d_in[14];
  const float* fc1w = (const float*)d_in[15];
  const float* fc1b = (const float*)d_in[16];
  const float* fc2w = (const float*)d_in[17];
  const float* fc2b = (const float*)d_in[18];
  const float* lnf_g = (const float*)d_in[19];
  const float* lnf_b = (const float*)d_in[20];

  char* wsp = (char*)d_ws;
  auto alloc = [&](size_t bytes) {
    char* p = wsp;
    wsp += (bytes + 255) & ~(size_t)255;
    return p;
  };
  unsigned short* wPatch = (unsigned short*)alloc((size_t)1024 * 1536 * 2);
  unsigned short* wQKV   = (unsigned short*)alloc((size_t)NLAYER * 3072 * 1024 * 2);
  unsigned short* wP     = (unsigned short*)alloc((size_t)NLAYER * HID * HID * 2);
  unsigned short* wF1    = (unsigned short*)alloc((size_t)NLAYER * MLPD * HID * 2);
  unsigned short* wF2    = (unsigned short*)alloc((size_t)NLAYER * HID * MLPD * 2);
  float*          qkvbias = (float*)alloc((size_t)NLAYER * 3072 * 4);
  unsigned short* Aim  = (unsigned short*)alloc((size_t)ROWS * CONVK * 2);
  float*          h    = (float*)alloc((size_t)ROWS * HID * 4);
  unsigned short* xnb  = (unsigned short*)alloc((size_t)ROWS * HID * 2);
  unsigned short* qkvo = (unsigned short*)alloc((size_t)ROWS * 3072 * 2);
  unsigned short* Qh   = (unsigned short*)alloc((size_t)ROWS * HID * 2);
  unsigned short* Kh   = (unsigned short*)alloc((size_t)ROWS * HID * 2);
  unsigned short* VT   = (unsigned short*)alloc((size_t)ROWS * HID * 2);
  unsigned short* ob   = (unsigned short*)alloc((size_t)ROWS * HID * 2);
  unsigned short* mb   = (unsigned short*)alloc((size_t)ROWS * MLPD * 2);

  auto cast = [&](const float* s, unsigned short* d, long long n) {
    long long n4 = n / 4;
    int grid = (int)((n4 + 255) / 256);
    if (grid > 16384) grid = 16384;
    cast4_k<<<grid, 256, 0, stream>>>(s, d, n4);
  };
  cast(patch_w, wPatch, (long long)1024 * 1536);
  castqkv_k<<<dim3(4096, 3), 256, 0, stream>>>(qw, kw, vw, wQKV);
  cast(pw, wP, (long long)NLAYER * HID * HID);
  cast(fc1w, wF1, (long long)NLAYER * MLPD * HID);
  cast(fc2w, wF2, (long long)NLAYER * HID * MLPD);
  biascat_k<<<48, 256, 0, stream>>>(qb, kb, vb, qkvbias);

  im2col_k<<<(ROWS * CONVK) / 256, 256, 0, stream>>>(pv, Aim);
  gemm_bt<0><<<dim3(HID / 128, (ROWS + 127) / 128), 256, 0, stream>>>(
      Aim, wPatch, patch_b, nullptr, h, nullptr, ROWS, HID, CONVK);

  for (int i = 0; i < NLAYER; ++i) {
    ln_k<1><<<ROWS, 256, 0, stream>>>(h, ln1_g + i * HID, ln1_b + i * HID, xnb, nullptr);
    gemm_bt<2><<<dim3(3072 / 128, (ROWS + 127) / 128), 256, 0, stream>>>(
        xnb, wQKV + (size_t)i * 3072 * 1024, qkvbias + i * 3072, nullptr, nullptr, qkvo,
        ROWS, 3072, HID);
    qkvprep_k<<<dim3(25, 32), 256, 0, stream>>>(qkvo, Qh, Kh, VT);
    flash2_k<<<dim3(32, 25), 256, 0, stream>>>(Qh, Kh, VT, ob);
    gemm_bt<1><<<dim3(HID / 128, (ROWS + 127) / 128), 256, 0, stream>>>(
        ob, wP + (size_t)i * HID * HID, pb + i * HID, h, h, nullptr, ROWS, HID, HID);
    ln_k<1><<<ROWS, 256, 0, stream>>>(h, ln2_g + i * HID, ln2_b + i * HID, xnb, nullptr);
    gemm_bt<3><<<dim3(MLPD / 128, (ROWS + 127) / 128), 256, 0, stream>>>(
        xnb, wF1 + (size_t)i * MLPD * HID, fc1b + i * MLPD, nullptr, nullptr, mb,
        ROWS, MLPD, HID);
    gemm_bt<1><<<dim3(HID / 128, (ROWS + 127) / 128), 256, 0, stream>>>(
        mb, wF2 + (size_t)i * HID * MLPD, fc2b + i * HID, h, h, nullptr, ROWS, HID, MLPD);
  }
  ln_k<0><<<ROWS, 256, 0, stream>>>(h, lnf_g, lnf_b, nullptr, (float*)d_out);
}